// Round 5
// baseline (1258.058 us; speedup 1.0000x reference)
//
#include <hip/hip_runtime.h>
#include <hip/hip_bf16.h>

// ---------------------------------------------------------------------------
// B=8, NT=32, NO=8, C=512, VD=1024, RD=300; No=512, Nr=2048.
// Inputs fp32. r-chain: split-bf16 (hi/lo planes PRE-SPLIT in global memory),
// 3-MFMA products, fp32 accum -> ~fp32 precision. o-branch + V-path: bf16.
// ---------------------------------------------------------------------------

typedef __attribute__((ext_vector_type(4))) float f32x4;
typedef __attribute__((ext_vector_type(8))) short bf16x8s;

#define TILE 128
#define BKK 32
#define LDSS 40  // bf16 LDS row stride (32+8)

__device__ inline void splt(float v, unsigned short& h, unsigned short& l) {
    __hip_bfloat16 hb = __float2bfloat16(v);
    float hf = __bfloat162float(hb);
    __hip_bfloat16 lb = __float2bfloat16(v - hf);
    h = *(unsigned short*)&hb;
    l = *(unsigned short*)&lb;
}

// ---------------- 3-plane split GEMM ---------------------------------------
// D = act(A@B + addN + addT^T + bias).  A = AH+AL (bf16 planes, (batch,M,K));
// BT = BTH+BTL (bf16 planes, (batch,N,K)).  Out: fp32 (DF) or planes (DH,DL).
// addN: H/L planes (M,N); addT: H/L planes (N,M); bias fp32.
__global__ __launch_bounds__(256) void gemm3p(
    const __hip_bfloat16* __restrict__ AH, const __hip_bfloat16* __restrict__ AL,
    long long sA, int lda,
    const __hip_bfloat16* __restrict__ BTH, const __hip_bfloat16* __restrict__ BTL,
    long long sBT, int ldbt,
    float* __restrict__ DF,
    __hip_bfloat16* __restrict__ DH, __hip_bfloat16* __restrict__ DL,
    long long sD, int ldd,
    const __hip_bfloat16* __restrict__ addNH, const __hip_bfloat16* __restrict__ addNL,
    long long sAddN, int ldaddN,
    const __hip_bfloat16* __restrict__ addTH, const __hip_bfloat16* __restrict__ addTL,
    long long sAddT, int ldaddT,
    const float* __restrict__ bias,
    int K, int relu)
{
    __shared__ __hip_bfloat16 Ahs[TILE * LDSS], Als[TILE * LDSS];
    __shared__ __hip_bfloat16 Bhs[TILE * LDSS], Bls[TILE * LDSS]; // [n][k]

    const int tid  = threadIdx.x;
    const int lane = tid & 63;
    const int wave = tid >> 6;
    const int wm   = (wave >> 1) * 64;
    const int wn   = (wave & 1) * 64;
    const int row0 = blockIdx.y * TILE;
    const int col0 = blockIdx.x * TILE;
    const int b    = blockIdx.z;

    const __hip_bfloat16* AHb = AH + (size_t)b * sA;
    const __hip_bfloat16* ALb = AL + (size_t)b * sA;
    const __hip_bfloat16* BHb = BTH + (size_t)b * sBT;
    const __hip_bfloat16* BLb = BTL + (size_t)b * sBT;

    f32x4 acc[4][4];
#pragma unroll
    for (int i = 0; i < 4; ++i)
#pragma unroll
        for (int j = 0; j < 4; ++j) acc[i][j] = (f32x4){0.f, 0.f, 0.f, 0.f};

    const int quad = lane >> 4;
    const int l16  = lane & 15;

    for (int k0 = 0; k0 < K; k0 += BKK) {
        __syncthreads();
#pragma unroll
        for (int it = 0; it < 2; ++it) {
            int task = tid + it * 256;
            int m = task >> 2, kq = task & 3;
            size_t go = (size_t)(row0 + m) * lda + k0 + kq * 8;
            *(uint4*)(&Ahs[m * LDSS + kq * 8]) = *(const uint4*)(AHb + go);
            *(uint4*)(&Als[m * LDSS + kq * 8]) = *(const uint4*)(ALb + go);
        }
#pragma unroll
        for (int it = 0; it < 2; ++it) {
            int task = tid + it * 256;
            int n = task >> 2, kq = task & 3;
            size_t go = (size_t)(col0 + n) * ldbt + k0 + kq * 8;
            *(uint4*)(&Bhs[n * LDSS + kq * 8]) = *(const uint4*)(BHb + go);
            *(uint4*)(&Bls[n * LDSS + kq * 8]) = *(const uint4*)(BLb + go);
        }
        __syncthreads();

        bf16x8s ah[4], al[4], bh[4], bl[4];
#pragma unroll
        for (int mt = 0; mt < 4; ++mt) {
            int r = (wm + mt * 16 + l16) * LDSS + quad * 8;
            ah[mt] = *(const bf16x8s*)(&Ahs[r]);
            al[mt] = *(const bf16x8s*)(&Als[r]);
        }
#pragma unroll
        for (int nt = 0; nt < 4; ++nt) {
            int r = (wn + nt * 16 + l16) * LDSS + quad * 8;
            bh[nt] = *(const bf16x8s*)(&Bhs[r]);
            bl[nt] = *(const bf16x8s*)(&Bls[r]);
        }
#pragma unroll
        for (int mt = 0; mt < 4; ++mt)
#pragma unroll
            for (int nt = 0; nt < 4; ++nt) {
                acc[mt][nt] = __builtin_amdgcn_mfma_f32_16x16x32_bf16(ah[mt], bh[nt], acc[mt][nt], 0, 0, 0);
                acc[mt][nt] = __builtin_amdgcn_mfma_f32_16x16x32_bf16(ah[mt], bl[nt], acc[mt][nt], 0, 0, 0);
                acc[mt][nt] = __builtin_amdgcn_mfma_f32_16x16x32_bf16(al[mt], bh[nt], acc[mt][nt], 0, 0, 0);
            }
    }

    float* DFb = DF ? DF + (size_t)b * sD : nullptr;
    __hip_bfloat16* DHb = DH ? DH + (size_t)b * sD : nullptr;
    __hip_bfloat16* DLb = DL ? DL + (size_t)b * sD : nullptr;
    const __hip_bfloat16* aNH = addNH ? addNH + (size_t)b * sAddN : nullptr;
    const __hip_bfloat16* aNL = addNL ? addNL + (size_t)b * sAddN : nullptr;
    const __hip_bfloat16* aTH = addTH ? addTH + (size_t)b * sAddT : nullptr;
    const __hip_bfloat16* aTL = addTL ? addTL + (size_t)b * sAddT : nullptr;
#pragma unroll
    for (int mt = 0; mt < 4; ++mt)
#pragma unroll
        for (int nt = 0; nt < 4; ++nt)
#pragma unroll
            for (int r = 0; r < 4; ++r) {
                int m = row0 + wm + mt * 16 + quad * 4 + r;
                int n = col0 + wn + nt * 16 + l16;
                float v = acc[mt][nt][r];
                if (aNH) v += __bfloat162float(aNH[(size_t)m * ldaddN + n])
                            + __bfloat162float(aNL[(size_t)m * ldaddN + n]);
                if (aTH) v += __bfloat162float(aTH[(size_t)n * ldaddT + m])
                            + __bfloat162float(aTL[(size_t)n * ldaddT + m]);
                if (bias) v += bias[n];
                if (relu && v < 0.f) v = 0.f;
                if (DFb) DFb[(size_t)m * ldd + n] = v;
                else {
                    unsigned short h, l;
                    splt(v, h, l);
                    ((unsigned short*)DHb)[(size_t)m * ldd + n] = h;
                    ((unsigned short*)DLb)[(size_t)m * ldd + n] = l;
                }
            }
}

// ---------------- fp32 -> H/L planes (elementwise, 8 per thread) ------------
__global__ void split_planes(const float* __restrict__ src,
                             __hip_bfloat16* __restrict__ H,
                             __hip_bfloat16* __restrict__ L, int n8)
{
    int i = blockIdx.x * blockDim.x + threadIdx.x;
    if (i >= n8) return;
    float4 v0 = ((const float4*)src)[i * 2];
    float4 v1 = ((const float4*)src)[i * 2 + 1];
    float vals[8] = {v0.x, v0.y, v0.z, v0.w, v1.x, v1.y, v1.z, v1.w};
    unsigned short hh[8], ll[8];
#pragma unroll
    for (int u = 0; u < 8; ++u) splt(vals[u], hh[u], ll[u]);
    *(uint4*)((unsigned short*)H + (size_t)i * 8) = *(uint4*)hh;
    *(uint4*)((unsigned short*)L + (size_t)i * 8) = *(uint4*)ll;
}

// ---------------- fp32 padded transpose -> H/L planes -----------------------
// src (R,C) zero-padded to (Rp,Cp); dst planes = transpose (Cp,Rp).
// Batched via blockIdx.z. Grid (Cp/64, Rp/64, batch), block 256.
__global__ __launch_bounds__(256) void padtrans_split(
    const float* __restrict__ src, __hip_bfloat16* __restrict__ dH,
    __hip_bfloat16* __restrict__ dL, int R, int C, int Rp, int Cp)
{
    __shared__ float T[64][65];
    const int t = threadIdx.x;
    const int tr = t >> 4, tc = t & 15;
    const int c0 = blockIdx.x * 64, r0 = blockIdx.y * 64;
    const size_t bat = blockIdx.z;
    const float* sb = src + bat * (size_t)R * C;
    unsigned short* dHb = (unsigned short*)dH + bat * (size_t)Cp * Rp;
    unsigned short* dLb = (unsigned short*)dL + bat * (size_t)Cp * Rp;

#pragma unroll
    for (int i = 0; i < 4; ++i) {
        int rr = tr + i * 16;
        int gr = r0 + rr;
        float v0 = 0.f, v1 = 0.f, v2 = 0.f, v3 = 0.f;
        if (gr < R) {
            int c = c0 + tc * 4;
            const float* s = sb + (size_t)gr * C + c;
            if (c + 0 < C) v0 = s[0];
            if (c + 1 < C) v1 = s[1];
            if (c + 2 < C) v2 = s[2];
            if (c + 3 < C) v3 = s[3];
        }
        T[rr][tc * 4 + 0] = v0; T[rr][tc * 4 + 1] = v1;
        T[rr][tc * 4 + 2] = v2; T[rr][tc * 4 + 3] = v3;
    }
    __syncthreads();
#pragma unroll
    for (int i = 0; i < 4; ++i) {
        int cc = tr + i * 16;
        unsigned short h[4], l[4];
#pragma unroll
        for (int u = 0; u < 4; ++u) splt(T[tc * 4 + u][cc], h[u], l[u]);
        size_t off = (size_t)(c0 + cc) * Rp + r0 + tc * 4;
        *(ushort4*)(dHb + off) = *(ushort4*)h;
        *(ushort4*)(dLb + off) = *(ushort4*)l;
    }
}

// ---------------- bf16 plane transpose (batched, plane via grid.z) ----------
// (R,C) -> (C,R). Grid (C/64, R/64, batch*2); z&1 selects plane.
__global__ __launch_bounds__(256) void trans_bf16(
    const __hip_bfloat16* __restrict__ sH, const __hip_bfloat16* __restrict__ sL,
    __hip_bfloat16* __restrict__ dH, __hip_bfloat16* __restrict__ dL,
    int R, int C)
{
    __shared__ unsigned short T[64][68];
    const int plane = blockIdx.z & 1;
    const size_t bat = blockIdx.z >> 1;
    const unsigned short* s = (const unsigned short*)(plane ? sL : sH) + bat * (size_t)R * C;
    unsigned short* d = (unsigned short*)(plane ? dL : dH) + bat * (size_t)R * C;
    const int t = threadIdx.x;
    const int tr = t >> 4, tc = t & 15;
    const int c0 = blockIdx.x * 64, r0 = blockIdx.y * 64;
#pragma unroll
    for (int i = 0; i < 4; ++i) {
        int rr = tr + i * 16;
        ushort4 v = *(const ushort4*)(s + (size_t)(r0 + rr) * C + c0 + tc * 4);
        T[rr][tc * 4 + 0] = v.x; T[rr][tc * 4 + 1] = v.y;
        T[rr][tc * 4 + 2] = v.z; T[rr][tc * 4 + 3] = v.w;
    }
    __syncthreads();
#pragma unroll
    for (int i = 0; i < 4; ++i) {
        int cc = tr + i * 16;
        ushort4 o = { T[tc * 4 + 0][cc], T[tc * 4 + 1][cc],
                      T[tc * 4 + 2][cc], T[tc * 4 + 3][cc] };
        *(ushort4*)(d + (size_t)(c0 + cc) * R + r0 + tc * 4) = o;
    }
}

// ---------------- plain bf16 GEMM (o-branch / V-path / epilogue) ------------
__global__ __launch_bounds__(256) void gemm_bf16(
    const __hip_bfloat16* __restrict__ A, long long sA, int lda,
    const __hip_bfloat16* __restrict__ B, long long sB, int ldb,
    void* __restrict__ D, long long sD, int ldd,
    const __hip_bfloat16* __restrict__ addsrc, long long sAdd, int ldadd,
    const float* __restrict__ bias,
    int K, int relu, int outF32)
{
    __shared__ __hip_bfloat16 As[TILE * LDSS];
    __shared__ __hip_bfloat16 Bs[TILE * LDSS]; // transposed: Bs[n][k]

    const int tid  = threadIdx.x;
    const int lane = tid & 63;
    const int wave = tid >> 6;
    const int wm   = (wave >> 1) * 64;
    const int wn   = (wave & 1) * 64;
    const int row0 = blockIdx.y * TILE;
    const int col0 = blockIdx.x * TILE;
    const int b    = blockIdx.z;

    const __hip_bfloat16* Ab = A + (size_t)b * sA;
    const __hip_bfloat16* Bb = B + (size_t)b * sB;

    f32x4 acc[4][4];
#pragma unroll
    for (int i = 0; i < 4; ++i)
#pragma unroll
        for (int j = 0; j < 4; ++j) acc[i][j] = (f32x4){0.f, 0.f, 0.f, 0.f};

    const int quad = lane >> 4;
    const int l16  = lane & 15;

    for (int k0 = 0; k0 < K; k0 += BKK) {
        __syncthreads();
#pragma unroll
        for (int it = 0; it < 2; ++it) {
            int task = tid + it * 256;
            int m = task >> 2, kq = task & 3;
            uint4 val = *(const uint4*)(Ab + (size_t)(row0 + m) * lda + k0 + kq * 8);
            *(uint4*)(&As[m * LDSS + kq * 8]) = val;
        }
#pragma unroll
        for (int it = 0; it < 2; ++it) {
            int task = tid + it * 256;
            int kk = task >> 4, n8 = task & 15;
            uint4 val = *(const uint4*)(Bb + (size_t)(k0 + kk) * ldb + col0 + n8 * 8);
            const __hip_bfloat16* v16 = (const __hip_bfloat16*)&val;
#pragma unroll
            for (int u = 0; u < 8; ++u)
                Bs[(n8 * 8 + u) * LDSS + kk] = v16[u];
        }
        __syncthreads();

        bf16x8s afrag[4], bfrag[4];
#pragma unroll
        for (int mt = 0; mt < 4; ++mt)
            afrag[mt] = *(const bf16x8s*)(&As[(wm + mt * 16 + l16) * LDSS + quad * 8]);
#pragma unroll
        for (int nt = 0; nt < 4; ++nt)
            bfrag[nt] = *(const bf16x8s*)(&Bs[(wn + nt * 16 + l16) * LDSS + quad * 8]);
#pragma unroll
        for (int mt = 0; mt < 4; ++mt)
#pragma unroll
            for (int nt = 0; nt < 4; ++nt)
                acc[mt][nt] = __builtin_amdgcn_mfma_f32_16x16x32_bf16(
                    afrag[mt], bfrag[nt], acc[mt][nt], 0, 0, 0);
    }

    __hip_bfloat16* Db16 = (__hip_bfloat16*)D + (size_t)b * sD;
    float*          DbF  = (float*)D + (size_t)b * sD;
    const __hip_bfloat16* Addb = addsrc ? addsrc + (size_t)b * sAdd : nullptr;
#pragma unroll
    for (int mt = 0; mt < 4; ++mt)
#pragma unroll
        for (int nt = 0; nt < 4; ++nt)
#pragma unroll
            for (int r = 0; r < 4; ++r) {
                int m = row0 + wm + mt * 16 + quad * 4 + r;
                int n = col0 + wn + nt * 16 + l16;
                float v = acc[mt][nt][r];
                if (Addb) v += __bfloat162float(Addb[(size_t)m * ldadd + n]);
                if (bias) v += bias[n];
                if (relu && v < 0.f) v = 0.f;
                if (outF32) DbF[(size_t)m * ldd + n] = v;
                else        Db16[(size_t)m * ldd + n] = __float2bfloat16(v);
            }
}

// fp32 -> bf16 converter (n divisible by 4)
__global__ void convert_kernel(const float* __restrict__ src,
                               __hip_bfloat16* __restrict__ dst, int n4)
{
    int i = blockIdx.x * blockDim.x + threadIdx.x;
    if (i >= n4) return;
    float4 v = ((const float4*)src)[i];
    __hip_bfloat16 t0 = __float2bfloat16(v.x), t1 = __float2bfloat16(v.y);
    __hip_bfloat16 t2 = __float2bfloat16(v.z), t3 = __float2bfloat16(v.w);
    ushort4 o = { *(unsigned short*)&t0, *(unsigned short*)&t1,
                  *(unsigned short*)&t2, *(unsigned short*)&t3 };
    ((ushort4*)dst)[i] = o;
}

// ---------------- fused segment attention + query-mean (fp32 q/k/v) ---------
__global__ __launch_bounds__(256) void attn_kernel(
    const float* __restrict__ q,
    const float* __restrict__ k,
    const float* __restrict__ v,
    __hip_bfloat16* __restrict__ abar)
{
    __shared__ float qs[8][512], ks[8][512], vs[8][512];
    __shared__ float sc[4][8][8];
    __shared__ float wb[4][8];

    const int tid  = threadIdx.x;
    const int mode = blockIdx.y;
    const int g    = blockIdx.x >> 3;
    const int idx  = blockIdx.x & 7;
    const int rowBase = g * 64;

    for (int t = tid; t < 512; t += 256) {
        int p = t >> 6, c8 = (t & 63) * 8;
        int row = (mode == 0) ? (rowBase + idx * 8 + p) : (rowBase + p * 8 + idx);
        const float* qp = q + (size_t)row * 512 + c8;
        const float* kp = k + (size_t)row * 512 + c8;
        const float* vp = v + (size_t)row * 512 + c8;
        *(float4*)(&qs[p][c8])     = *(const float4*)(qp);
        *(float4*)(&qs[p][c8 + 4]) = *(const float4*)(qp + 4);
        *(float4*)(&ks[p][c8])     = *(const float4*)(kp);
        *(float4*)(&ks[p][c8 + 4]) = *(const float4*)(kp + 4);
        *(float4*)(&vs[p][c8])     = *(const float4*)(vp);
        *(float4*)(&vs[p][c8 + 4]) = *(const float4*)(vp + 4);
    }
    __syncthreads();

    {
        int h = tid >> 6, l = tid & 63;
        int i = l >> 3, j = l & 7;
        const float* qrow = &qs[i][h * 128];
        const float* krow = &ks[j][h * 128];
        float s = 0.f;
#pragma unroll
        for (int d = 0; d < 128; d += 4) {
            float4 qa = *(const float4*)(qrow + d);
            float4 kb = *(const float4*)(krow + d);
            s += qa.x * kb.x + qa.y * kb.y + qa.z * kb.z + qa.w * kb.w;
        }
        sc[h][i][j] = s * 0.08838834764831845f;
    }
    __syncthreads();

    if (tid < 32) {
        int h = tid >> 3, i = tid & 7;
        float mx = -1e30f;
#pragma unroll
        for (int j = 0; j < 8; ++j) mx = fmaxf(mx, sc[h][i][j]);
        float e[8], sum = 0.f;
#pragma unroll
        for (int j = 0; j < 8; ++j) { e[j] = __expf(sc[h][i][j] - mx); sum += e[j]; }
        float inv = 1.f / sum;
#pragma unroll
        for (int j = 0; j < 8; ++j) sc[h][i][j] = e[j] * inv;
    }
    __syncthreads();

    if (tid < 32) {
        int h = tid >> 3, j = tid & 7;
        float s = 0.f;
#pragma unroll
        for (int i = 0; i < 8; ++i) s += sc[h][i][j];
        wb[h][j] = s * 0.125f;
    }
    __syncthreads();

    {
        int orow = g * 16 + mode * 8 + idx;
        for (int c = tid; c < 512; c += 256) {
            int h = c >> 7;
            float o = 0.f;
#pragma unroll
            for (int j = 0; j < 8; ++j) o += wb[h][j] * vs[j][c];
            abar[(size_t)orow * 512 + c] = __float2bfloat16(o);
        }
    }
}

// ---------------------------------------------------------------------------

extern "C" void kernel_launch(void* const* d_in, const int* in_sizes, int n_in,
                              void* d_out, int out_size, void* d_ws, size_t ws_size,
                              hipStream_t stream)
{
    const float* Ao   = (const float*)d_in[0];   // (8,512,512)
    const float* srco = (const float*)d_in[1];   // (4096,1024)
    const float* Ar   = (const float*)d_in[2];   // (8,2048,2048)
    const float* srcr = (const float*)d_in[3];   // (16384,300)
    const float* Wo1  = (const float*)d_in[4];   // (1024,1024)
    const float* Wo2  = (const float*)d_in[5];   // (1024,512)
    const float* Wr1  = (const float*)d_in[6];   // (300,1024)
    const float* Wr2  = (const float*)d_in[7];   // (1024,512)
    const float* Wq   = (const float*)d_in[8];
    const float* bq   = (const float*)d_in[9];
    const float* Wk   = (const float*)d_in[10];
    const float* bk   = (const float*)d_in[11];
    const float* Wv   = (const float*)d_in[12];
    const float* bv   = (const float*)d_in[13];
    const float* Wp   = (const float*)d_in[14];
    const float* bp   = (const float*)d_in[15];
    const float* We   = (const float*)d_in[16];  // (1024,512)
    const float* be   = (const float*)d_in[17];
    float* out = (float*)d_out;                  // (4096,512) fp32

    char* ws = (char*)d_ws;
    // Offsets (bytes), lifetime-safe overlap (see per-stage notes below):
    __hip_bfloat16* ArH   = (__hip_bfloat16*)(ws + 0);           // 67.1MB, dies after GR
    __hip_bfloat16* ArL   = (__hip_bfloat16*)(ws + 67108864);    // 67.1MB
    __hip_bfloat16* XPTH  = (__hip_bfloat16*)(ws + 134217728);   // 12.6MB, dies after U
    __hip_bfloat16* XPTL  = (__hip_bfloat16*)(ws + 146800640);
    __hip_bfloat16* UH    = (__hip_bfloat16*)(ws + 159383552);   // 12.6MB, dies after HR
    __hip_bfloat16* UL    = (__hip_bfloat16*)(ws + 171966464);
    __hip_bfloat16* HRH   = (__hip_bfloat16*)(ws + 184549376);   // 33.6MB, dies after T2R
    __hip_bfloat16* HRL   = (__hip_bfloat16*)(ws + 218103808);
    __hip_bfloat16* T2RH  = (__hip_bfloat16*)(ws + 134217728);   // over XPT/U-start (dead)
    __hip_bfloat16* T2RL  = (__hip_bfloat16*)(ws + 150994944);
    __hip_bfloat16* T2RTH = (__hip_bfloat16*)(ws + 167772160);   // over U-end/HRH (dead)
    __hip_bfloat16* T2RTL = (__hip_bfloat16*)(ws + 184549376);
    __hip_bfloat16* GRH   = (__hip_bfloat16*)(ws + 201326592);   // over HRL (dead)
    __hip_bfloat16* GRL   = (__hip_bfloat16*)(ws + 218103808);
    float* qF = (float*)(ws + 0);                                // over Ar (dead after GR)
    float* kF = (float*)(ws + 33554432);
    float* vF = (float*)(ws + 67108864);
    __hip_bfloat16* ABAR  = (__hip_bfloat16*)(ws + 100663296);   // 4.2MB
    // o-branch pool (runs after attn; over T2R planes, dead):
    __hip_bfloat16* TO    = (__hip_bfloat16*)(ws + 104857600);
    __hip_bfloat16* HO    = (__hip_bfloat16*)(ws + 113246208);
    __hip_bfloat16* T2O   = (__hip_bfloat16*)(ws + 121634816);
    __hip_bfloat16* CAT   = (__hip_bfloat16*)(ws + 125829120);
    __hip_bfloat16* srcoB = (__hip_bfloat16*)(ws + 134217728);
    __hip_bfloat16* AoB   = (__hip_bfloat16*)(ws + 142606336);
    __hip_bfloat16* Wo1B  = (__hip_bfloat16*)(ws + 146800640);
    __hip_bfloat16* Wo2B  = (__hip_bfloat16*)(ws + 148897792);
    __hip_bfloat16* WeB   = (__hip_bfloat16*)(ws + 149946368);
    __hip_bfloat16* WpB   = (__hip_bfloat16*)(ws + 150994944);
    // weight planes (persistent):
    __hip_bfloat16* WPTH  = (__hip_bfloat16*)(ws + 251658240);   // (1024,320)
    __hip_bfloat16* WPTL  = (__hip_bfloat16*)(ws + 252313600);
    __hip_bfloat16* Wr2TH = (__hip_bfloat16*)(ws + 252968960);   // (512,1024)
    __hip_bfloat16* Wr2TL = (__hip_bfloat16*)(ws + 254017536);
    __hip_bfloat16* WqTH  = (__hip_bfloat16*)(ws + 255066112);   // (512,512)
    __hip_bfloat16* WqTL  = (__hip_bfloat16*)(ws + 255590400);
    __hip_bfloat16* WkTH  = (__hip_bfloat16*)(ws + 256114688);
    __hip_bfloat16* WkTL  = (__hip_bfloat16*)(ws + 256638976);
    __hip_bfloat16* WvB   = (__hip_bfloat16*)(ws + 257163264);   // (512,512)

    dim3 blk(256);
    auto cvt = [&](const float* s, __hip_bfloat16* d, int n) {
        convert_kernel<<<dim3((n / 4 + 255) / 256), blk, 0, stream>>>(s, d, n / 4);
    };

    // ---- pre-splits / transposes ----
    split_planes<<<dim3(33554432 / 8 / 256), blk, 0, stream>>>(Ar, ArH, ArL, 33554432 / 8);
    // XPT (8: 384x2048) from srcr viewed (8,2048,300)
    padtrans_split<<<dim3(6, 32, 8), blk, 0, stream>>>(srcr, XPTH, XPTL, 2048, 300, 2048, 384);
    // WPT (1024,320) from Wr1 (300,1024)
    padtrans_split<<<dim3(16, 5, 1), blk, 0, stream>>>(Wr1, WPTH, WPTL, 300, 1024, 320, 1024);
    // Wr2T (512,1024), WqT/WkT (512,512)
    padtrans_split<<<dim3(8, 16, 1), blk, 0, stream>>>(Wr2, Wr2TH, Wr2TL, 1024, 512, 1024, 512);
    padtrans_split<<<dim3(8, 8, 1), blk, 0, stream>>>(Wq, WqTH, WqTL, 512, 512, 512, 512);
    padtrans_split<<<dim3(8, 8, 1), blk, 0, stream>>>(Wk, WkTH, WkTL, 512, 512, 512, 512);
    cvt(Wv, WvB, 262144);

    // ---- r-branch (split precision via planes) ----
    // U = Ar@XP + XP^T-add   (8: 2048x2048 @ 2048x384) -> planes
    gemm3p<<<dim3(3, 16, 8), blk, 0, stream>>>(
        ArH, ArL, 2048LL * 2048, 2048, XPTH, XPTL, 384LL * 2048, 2048,
        nullptr, UH, UL, 2048LL * 384, 384,
        nullptr, nullptr, 0, 0, XPTH, XPTL, 384LL * 2048, 2048,
        nullptr, 2048, 0);
    // HR = relu(U@WP)   (16384x320 @ 320x1024) -> planes
    gemm3p<<<dim3(8, 128, 1), blk, 0, stream>>>(
        UH, UL, 0, 384, WPTH, WPTL, 0, 320,
        nullptr, HRH, HRL, 0, 1024,
        nullptr, nullptr, 0, 0, nullptr, nullptr, 0, 0,
        nullptr, 320, 1);
    // T2R = HR@Wr2   (16384x1024 @ 1024x512) -> planes
    gemm3p<<<dim3(4, 128, 1), blk, 0, stream>>>(
        HRH, HRL, 0, 1024, Wr2TH, Wr2TL, 0, 1024,
        nullptr, T2RH, T2RL, 0, 512,
        nullptr, nullptr, 0, 0, nullptr, nullptr, 0, 0,
        nullptr, 1024, 0);
    // T2RT planes (8: 512x2048) from T2R viewed (8,2048,512)
    trans_bf16<<<dim3(8, 32, 16), blk, 0, stream>>>(T2RH, T2RL, T2RTH, T2RTL, 2048, 512);
    // GR = relu(Ar@T2R + T2R)   (8: 2048x2048 @ 2048x512) -> planes
    gemm3p<<<dim3(4, 16, 8), blk, 0, stream>>>(
        ArH, ArL, 2048LL * 2048, 2048, T2RTH, T2RTL, 512LL * 2048, 2048,
        nullptr, GRH, GRL, 2048LL * 512, 512,
        T2RH, T2RL, 2048LL * 512, 512, nullptr, nullptr, 0, 0,
        nullptr, 2048, 1);
    // q/k = GR @ Wq/Wk + b   (16384x512 @ 512x512) -> fp32
    gemm3p<<<dim3(4, 128, 1), blk, 0, stream>>>(
        GRH, GRL, 0, 512, WqTH, WqTL, 0, 512,
        qF, nullptr, nullptr, 0, 512,
        nullptr, nullptr, 0, 0, nullptr, nullptr, 0, 0,
        bq, 512, 0);
    gemm3p<<<dim3(4, 128, 1), blk, 0, stream>>>(
        GRH, GRL, 0, 512, WkTH, WkTL, 0, 512,
        kF, nullptr, nullptr, 0, 512,
        nullptr, nullptr, 0, 0, nullptr, nullptr, 0, 0,
        bk, 512, 0);
    // v = GRH @ Wv + bv  (plain bf16, fp32 out)
    gemm_bf16<<<dim3(4, 128, 1), blk, 0, stream>>>(
        GRH, 0, 512, WvB, 0, 512, vF, 0, 512,
        nullptr, 0, 0, bv, 512, 0, 1);
    // fused attention + query-mean -> ABAR bf16 (4096,512)
    attn_kernel<<<dim3(2048, 2), blk, 0, stream>>>(qF, kF, vF, ABAR);

    // ---- o-branch (bf16) ----
    cvt(srco, srcoB, 4194304);
    cvt(Ao, AoB, 2097152);
    cvt(Wo1, Wo1B, 1048576);
    cvt(Wo2, Wo2B, 524288);
    cvt(We, WeB, 524288);
    cvt(Wp, WpB, 262144);
    // TO = srco @ Wo1  (4096,1024)@(1024,1024)
    gemm_bf16<<<dim3(8, 32, 1), blk, 0, stream>>>(srcoB, 0, 1024, Wo1B, 0, 1024,
        TO, 0, 1024, nullptr, 0, 0, nullptr, 1024, 0, 0);
    // HO = relu(Ao@TO + TO)  batched 8
    gemm_bf16<<<dim3(8, 4, 8), blk, 0, stream>>>(AoB, 512LL * 512, 512, TO, 512LL * 1024, 1024,
        HO, 512LL * 1024, 1024, TO, 512LL * 1024, 1024, nullptr, 512, 1, 0);
    // T2O = HO @ Wo2  (4096,1024)@(1024,512)
    gemm_bf16<<<dim3(4, 32, 1), blk, 0, stream>>>(HO, 0, 1024, Wo2B, 0, 512,
        T2O, 0, 512, nullptr, 0, 0, nullptr, 1024, 0, 0);
    // g_o = relu(Ao@T2O + T2O) -> CAT right half
    gemm_bf16<<<dim3(4, 4, 8), blk, 0, stream>>>(AoB, 512LL * 512, 512, T2O, 512LL * 512, 512,
        (void*)(CAT + 512), 512LL * 1024, 1024, T2O, 512LL * 512, 512, nullptr, 512, 1, 0);
    // P = ABAR @ Wp + bp -> CAT left half
    gemm_bf16<<<dim3(4, 32, 1), blk, 0, stream>>>(ABAR, 0, 512, WpB, 0, 512,
        CAT, 0, 1024, nullptr, 0, 0, bp, 512, 0, 0);
    // out = CAT @ We + be  -> fp32
    gemm_bf16<<<dim3(4, 32, 1), blk, 0, stream>>>(CAT, 0, 1024, WeB, 0, 512,
        out, 0, 512, nullptr, 0, 0, be, 1024, 0, 1);
}